// Round 21
// baseline (53.386 us; speedup 1.0000x reference)
//
#include <hip/hip_runtime.h>

#define DYN 16
#define DON 256
#define DIN 256
#define BSN 4096
#define NF 4096   /* DY*DI feature rows */
#define KTOT 512  /* concat K = 2*DI */

typedef unsigned short u16;
typedef __attribute__((ext_vector_type(8))) short bf16x8;
typedef __attribute__((ext_vector_type(4))) float f32x4;
typedef __attribute__((ext_vector_type(4))) unsigned short u16x4;

static __device__ __forceinline__ u16 f2bf(float f) {
  unsigned u = __builtin_bit_cast(unsigned, f);
  u += 0x7fffu + ((u >> 16) & 1u);
  return (u16)(u >> 16);
}
static __device__ __forceinline__ float bf2f(u16 h) {
  unsigned u = ((unsigned)h) << 16;
  return __builtin_bit_cast(float, u);
}

// ---------------------------------------------------------------------------
// Kernel 1 (fused pre-pass, 2048 blocks) - R19 winning state (unchanged):
//  blocks 0..1023: fold rms into weights, concat [Wu | Wl(rev-rms)], bf16.
//  blocks 1024..2047: 128x128 tiled transpose of x w/ f32->bf16 + per-column
//    sum(x^2) partials. LDS XOR swizzle b ^ ((f>>3)<<2): 2-way banks (free),
//    measured -4.4us vs the 4-way stagger.
// ---------------------------------------------------------------------------
__global__ __launch_bounds__(256) void k_pre(
    const float* __restrict__ x, const float* __restrict__ wu,
    const float* __restrict__ wl, const float* __restrict__ rms,
    u16* __restrict__ aprep, u16* __restrict__ xbf,
    float* __restrict__ partial) {
  __shared__ u16 tile[128 * 132];
  const int t = threadIdx.x;
  if (blockIdx.x < 1024) {
    int e = blockIdx.x * 256 + t;
    int row = e >> 6;
    int k0 = (e & 63) << 3;
    int d = row >> 8;
    const float* src;
    const float* rp;
    if (k0 < 256) {
      src = wu + (size_t)row * 256 + k0;
      rp  = rms + d * 256 + k0;
    } else {
      src = wl + (size_t)row * 256 + (k0 - 256);
      rp  = rms + (DYN - 1 - d) * 256 + (k0 - 256);
    }
    float4 s0 = *reinterpret_cast<const float4*>(src);
    float4 s1 = *reinterpret_cast<const float4*>(src + 4);
    float4 r0 = *reinterpret_cast<const float4*>(rp);
    float4 r1 = *reinterpret_cast<const float4*>(rp + 4);
    bf16x8 o;
    o[0] = (short)f2bf(s0.x * r0.x); o[1] = (short)f2bf(s0.y * r0.y);
    o[2] = (short)f2bf(s0.z * r0.z); o[3] = (short)f2bf(s0.w * r0.w);
    o[4] = (short)f2bf(s1.x * r1.x); o[5] = (short)f2bf(s1.y * r1.y);
    o[6] = (short)f2bf(s1.z * r1.z); o[7] = (short)f2bf(s1.w * r1.w);
    *reinterpret_cast<bf16x8*>(aprep + (size_t)row * KTOT + k0) = o;
    return;
  }
  const int bid = blockIdx.x - 1024;
  const int bt = bid & 31, ft = bid >> 5;
  const float* xb = x + (size_t)ft * 128 * BSN + bt * 128;
  const int frow = t >> 5, b4 = (t & 31) * 4;
  #pragma unroll
  for (int p = 0; p < 16; ++p) {
    int f = p * 8 + frow;
    float4 v = *reinterpret_cast<const float4*>(xb + (size_t)f * BSN + b4);
    u16x4 h;
    h[0] = f2bf(v.x); h[1] = f2bf(v.y); h[2] = f2bf(v.z); h[3] = f2bf(v.w);
    *reinterpret_cast<u16x4*>(&tile[f * 132 + (b4 ^ ((f >> 3) << 2))]) = h;
  }
  __syncthreads();
  const int chunk = t & 15;
  const int bg = t >> 4;
  #pragma unroll
  for (int p = 0; p < 8; ++p) {
    int b = bg + p * 16;
    float s = 0.f;
    bf16x8 w;
    #pragma unroll
    for (int j = 0; j < 8; ++j) {
      int r = chunk * 8 + j;
      u16 v = tile[r * 132 + (b ^ ((r >> 3) << 2))];
      float xv = bf2f(v);
      s += xv * xv;
      w[j] = (short)v;
    }
    *reinterpret_cast<bf16x8*>(
        xbf + (size_t)(bt * 128 + b) * NF + ft * 128 + chunk * 8) = w;
    #pragma unroll
    for (int m = 1; m < 16; m <<= 1) s += __shfl_xor(s, m, 64);
    if (chunk == 0) partial[ft * BSN + bt * 128 + b] = s;
  }
}

// ---------------------------------------------------------------------------
// Kernel 2: bf16 MFMA GEMM, 128b x 256f tiles, 512 blocks of 256 threads,
// 2 BLOCKS/CU with NO VGPR squeeze (R14's confound: launch_bounds(512,4)
// capped VGPR at 128 on a ~180-VGPR kernel -> spills; here 4 waves/block,
// launch_bounds(256,2) -> 256-VGPR cap, est ~210 used).
// Mechanism: two co-resident blocks have independent barriers; one block's
// serial epilogue store burst (~9.4us at 1 blk/CU lockstep) and prologue
// fill overlap the partner's K-loop (m114 cross-wave MFMA||VMEM overlap).
// Per-SIMD issue mix identical to the 50.05us R20 state (2 waves/SIMD,
// 12 ds_read_b128 + 6 stage loads + 32 MFMA per wave per K-step).
// Wave tile 64b x 128f, acc[4][8]=128 VGPR. BK=32, 16 K-steps. 3-slot
// 24KB ring (A 8KB + B 16KB), boundary s_waitcnt vmcnt(6) (6 loads/stage,
// 2 stages in flight - never drains mid-loop). Involution chunk swizzle
// (identical read/write mask algebra, verified for 256-row B tiles).
// fc folded in prologue. XCD map bid&7 = d-pair. LDS 74240 x 2 = 145KB.
// Epilogue: float4 batch-contiguous stores, relu(fc[b]*acc + bias[f]).
// ---------------------------------------------------------------------------
__global__ __launch_bounds__(256, 2) void k_gemm(
    const u16* __restrict__ aprep, const u16* __restrict__ xbf,
    const float* __restrict__ partial, const float* __restrict__ bias,
    float* __restrict__ out) {
  extern __shared__ char smem[];
  float* fcl = (float*)(smem + 73728);       // 128 floats
  const int bid = blockIdx.x;
  const int dp = bid & 7;                    // d-pair -> XCD
  const int s = bid >> 3;
  const int d = (s & 1) ? (15 - dp) : dp;
  const int bt = s >> 1;                     // 0..31 batch tile (128 b)
  const int b0 = bt * 128;
  const int fr0 = d * 256;
  const int t = threadIdx.x;
  const int wave = t >> 6, lane = t & 63;
  const int lhi = lane >> 4, llo = lane & 15;
  const int wm = wave >> 1, wn = wave & 1;   // 2 batch-halves x 2 f-halves
  const int kmask = ((llo >> 1) & 7) << 4;

  f32x4 acc[4][8];
  #pragma unroll
  for (int m = 0; m < 4; ++m)
    #pragma unroll
    for (int n = 0; n < 8; ++n)
      acc[m][n] = f32x4{0.f, 0.f, 0.f, 0.f};

  // stage one K-step: A (x, 128b x 32k = 8KB, 2 loads) + B (W, 256f x 32k
  // = 16KB, 4 loads). 6 loads/thread/step.
  auto stage = [&](int slot, int kt) {
    const int fbase = (kt < 8) ? (d * 256 + kt * 32)
                               : ((15 - d) * 256 + (kt - 8) * 32);
    #pragma unroll
    for (int j = 0; j < 2; ++j) {
      int c = j * 256 + t;              // physical 16B chunk (0..511)
      int cl = c ^ ((c >> 3) & 7);      // logical chunk (involution)
      int r = cl >> 2, kc = cl & 3;     // batch row / k-octet
      const u16* g = xbf + (size_t)(b0 + r) * NF + fbase + kc * 8;
      unsigned lbase = (unsigned)(slot * 24576 + (j * 256 + wave * 64) * 16);
      __builtin_amdgcn_global_load_lds(
          (const __attribute__((address_space(1))) unsigned int*)g,
          (__attribute__((address_space(3))) unsigned int*)(smem + lbase),
          16, 0, 0);
    }
    #pragma unroll
    for (int j = 0; j < 4; ++j) {
      int c = j * 256 + t;              // physical 16B chunk (0..1023)
      int cl = c ^ ((c >> 3) & 7);
      int r = cl >> 2, kc = cl & 3;     // f row 0..255 / k-octet
      const u16* g = aprep + (size_t)(fr0 + r) * KTOT + kt * 32 + kc * 8;
      unsigned lbase = (unsigned)(slot * 24576 + 8192 +
                                  (j * 256 + wave * 64) * 16);
      __builtin_amdgcn_global_load_lds(
          (const __attribute__((address_space(1))) unsigned int*)g,
          (__attribute__((address_space(3))) unsigned int*)(smem + lbase),
          16, 0, 0);
    }
  };

  // fc for this block's 128 batches (overlaps staging latency)
  if (t < 128) {
    float fs = 0.f;
    #pragma unroll
    for (int i = 0; i < 32; ++i) fs += partial[i * BSN + b0 + t];
    fcl[t] = rsqrtf(fs * (1.0f / 4096.0f) + 1e-6f);
  }
  stage(0, 0);
  stage(1, 1);
  asm volatile("s_waitcnt vmcnt(6)\n\ts_barrier" ::: "memory");

  for (int kt = 0; kt < 16; ++kt) {
    const int slot = kt % 3;
    const char* sA = (const char*)smem + slot * 24576;
    const char* sB = sA + 8192;
    if (kt < 14) stage((kt + 2) % 3, kt + 2);

    bf16x8 af[4], bq[8];
    #pragma unroll
    for (int m = 0; m < 4; ++m) {
      int row = wm * 64 + m * 16 + llo;
      af[m] = *reinterpret_cast<const bf16x8*>(
          sA + ((row * 64 + lhi * 16) ^ kmask));
    }
    #pragma unroll
    for (int n = 0; n < 8; ++n) {
      int row = wn * 128 + n * 16 + llo;
      bq[n] = *reinterpret_cast<const bf16x8*>(
          sB + ((row * 64 + lhi * 16) ^ kmask));
    }
    __builtin_amdgcn_s_setprio(1);
    #pragma unroll
    for (int m = 0; m < 4; ++m)
      #pragma unroll
      for (int n = 0; n < 8; ++n)
        acc[m][n] = __builtin_amdgcn_mfma_f32_16x16x32_bf16(
            af[m], bq[n], acc[m][n], 0, 0, 0);
    __builtin_amdgcn_s_setprio(0);

    if (kt < 14) {
      asm volatile("s_waitcnt vmcnt(6)\n\ts_barrier" ::: "memory");
    } else if (kt == 14) {
      asm volatile("s_waitcnt vmcnt(0)\n\ts_barrier" ::: "memory");
    }
  }

  // epilogue: y[f][b] = relu(fc[b]*acc + bias[f]), float4 over batch
  #pragma unroll
  for (int m = 0; m < 4; ++m) {
    int lb = wm * 64 + m * 16 + lhi * 4;
    float4 fq = *reinterpret_cast<const float4*>(&fcl[lb]);
    #pragma unroll
    for (int n = 0; n < 8; ++n) {
      int fo = fr0 + wn * 128 + n * 16 + llo;
      float bv = bias[fo];
      float4 v;
      v.x = fmaxf(acc[m][n][0] * fq.x + bv, 0.f);
      v.y = fmaxf(acc[m][n][1] * fq.y + bv, 0.f);
      v.z = fmaxf(acc[m][n][2] * fq.z + bv, 0.f);
      v.w = fmaxf(acc[m][n][3] * fq.w + bv, 0.f);
      *reinterpret_cast<float4*>(out + (size_t)fo * BSN + b0 + lb) = v;
    }
  }
}

extern "C" void kernel_launch(void* const* d_in, const int* in_sizes, int n_in,
                              void* d_out, int out_size, void* d_ws, size_t ws_size,
                              hipStream_t stream) {
  (void)in_sizes; (void)n_in; (void)out_size; (void)ws_size;
  const float* x    = (const float*)d_in[0];
  const float* rms  = (const float*)d_in[1];
  const float* wu   = (const float*)d_in[2];
  const float* wl   = (const float*)d_in[3];
  const float* bias = (const float*)d_in[4];
  float* out = (float*)d_out;

  char* ws = (char*)d_ws;
  u16* xbf      = (u16*)ws;                      // 32 MiB  (x^T bf16)
  u16* aprep    = (u16*)(ws + 33554432);         // 4 MiB   (folded weights)
  float* partial = (float*)(ws + 37748736);      // 512 KiB (sumsq partials)

  k_pre<<<2048, 256, 0, stream>>>(x, wu, wl, rms, aprep, xbf, partial);
  k_gemm<<<512, 256, 74240, stream>>>(aprep, xbf, partial, bias, out);
}

// Round 22
// 49.690 us; speedup vs baseline: 1.0744x; 1.0744x over previous
//
#include <hip/hip_runtime.h>

#define DYN 16
#define DON 256
#define DIN 256
#define BSN 4096
#define NF 4096   /* DY*DI feature rows */
#define KTOT 512  /* concat K = 2*DI */

typedef unsigned short u16;
typedef __attribute__((ext_vector_type(8))) short bf16x8;
typedef __attribute__((ext_vector_type(4))) float f32x4;
typedef __attribute__((ext_vector_type(4))) unsigned short u16x4;

static __device__ __forceinline__ u16 f2bf(float f) {
  unsigned u = __builtin_bit_cast(unsigned, f);
  u += 0x7fffu + ((u >> 16) & 1u);
  return (u16)(u >> 16);
}
static __device__ __forceinline__ float bf2f(u16 h) {
  unsigned u = ((unsigned)h) << 16;
  return __builtin_bit_cast(float, u);
}

// ---------------------------------------------------------------------------
// Kernel 1 (fused pre-pass, 2048 blocks) - R19 winning state:
//  blocks 0..1023: fold rms into weights, concat [Wu | Wl(rev-rms)], bf16.
//  blocks 1024..2047: 128x128 tiled transpose of x w/ f32->bf16 + per-column
//    sum(x^2) partials. LDS XOR swizzle b ^ ((f>>3)<<2): 2-way banks (free),
//    measured -4.4us vs the 4-way stagger.
// ---------------------------------------------------------------------------
__global__ __launch_bounds__(256) void k_pre(
    const float* __restrict__ x, const float* __restrict__ wu,
    const float* __restrict__ wl, const float* __restrict__ rms,
    u16* __restrict__ aprep, u16* __restrict__ xbf,
    float* __restrict__ partial) {
  __shared__ u16 tile[128 * 132];
  const int t = threadIdx.x;
  if (blockIdx.x < 1024) {
    int e = blockIdx.x * 256 + t;
    int row = e >> 6;
    int k0 = (e & 63) << 3;
    int d = row >> 8;
    const float* src;
    const float* rp;
    if (k0 < 256) {
      src = wu + (size_t)row * 256 + k0;
      rp  = rms + d * 256 + k0;
    } else {
      src = wl + (size_t)row * 256 + (k0 - 256);
      rp  = rms + (DYN - 1 - d) * 256 + (k0 - 256);
    }
    float4 s0 = *reinterpret_cast<const float4*>(src);
    float4 s1 = *reinterpret_cast<const float4*>(src + 4);
    float4 r0 = *reinterpret_cast<const float4*>(rp);
    float4 r1 = *reinterpret_cast<const float4*>(rp + 4);
    bf16x8 o;
    o[0] = (short)f2bf(s0.x * r0.x); o[1] = (short)f2bf(s0.y * r0.y);
    o[2] = (short)f2bf(s0.z * r0.z); o[3] = (short)f2bf(s0.w * r0.w);
    o[4] = (short)f2bf(s1.x * r1.x); o[5] = (short)f2bf(s1.y * r1.y);
    o[6] = (short)f2bf(s1.z * r1.z); o[7] = (short)f2bf(s1.w * r1.w);
    *reinterpret_cast<bf16x8*>(aprep + (size_t)row * KTOT + k0) = o;
    return;
  }
  const int bid = blockIdx.x - 1024;
  const int bt = bid & 31, ft = bid >> 5;
  const float* xb = x + (size_t)ft * 128 * BSN + bt * 128;
  const int frow = t >> 5, b4 = (t & 31) * 4;
  #pragma unroll
  for (int p = 0; p < 16; ++p) {
    int f = p * 8 + frow;
    float4 v = *reinterpret_cast<const float4*>(xb + (size_t)f * BSN + b4);
    u16x4 h;
    h[0] = f2bf(v.x); h[1] = f2bf(v.y); h[2] = f2bf(v.z); h[3] = f2bf(v.w);
    *reinterpret_cast<u16x4*>(&tile[f * 132 + (b4 ^ ((f >> 3) << 2))]) = h;
  }
  __syncthreads();
  const int chunk = t & 15;
  const int bg = t >> 4;
  #pragma unroll
  for (int p = 0; p < 8; ++p) {
    int b = bg + p * 16;
    float s = 0.f;
    bf16x8 w;
    #pragma unroll
    for (int j = 0; j < 8; ++j) {
      int r = chunk * 8 + j;
      u16 v = tile[r * 132 + (b ^ ((r >> 3) << 2))];
      float xv = bf2f(v);
      s += xv * xv;
      w[j] = (short)v;
    }
    *reinterpret_cast<bf16x8*>(
        xbf + (size_t)(bt * 128 + b) * NF + ft * 128 + chunk * 8) = w;
    #pragma unroll
    for (int m = 1; m < 16; m <<= 1) s += __shfl_xor(s, m, 64);
    if (chunk == 0) partial[ft * BSN + bt * 128 + b] = s;
  }
}

// ---------------------------------------------------------------------------
// Kernel 2: bf16 MFMA GEMM - R20 session-best state (50.05us total).
// R10 4-phase structure with redundant intra-K-step barriers removed (R20
// measured: removal is safe and neutral-to-slightly-positive).
// 256 blocks = 1/CU, 8 waves (2Mx4N), wave tile 128x64, BK=32, 16 K-steps,
// 3-slot 32KB LDS ring; only the boundary s_waitcnt vmcnt(4)+s_barrier per
// K-step (counted - never drains mid-loop; vmcnt(0) at kt14 tail).
// Correctness: within K-step kt waves READ slot kt%3 and WRITE (gload_lds)
// slot (kt+2)%3 - disjoint; RAW on slot kt guaranteed by the kt-1 boundary
// (vmcnt(4) retires stage(kt)); WAR guaranteed because staged-slot writes
// issue only after the boundary barrier following its last reads.
// Involution swizzle chunk^((chunk>>3)&7) at pre-swizzled gload source +
// XOR'd ds_read (R2-measured zero-conflict). setprio around MFMA clusters.
// fc folded in prologue. XCD map bid&7 = d-pair (L2-fit working set).
// Epilogue: float4 batch-contiguous stores, relu(fc[b]*acc + bias[f])
// (R8 silicon-verified C-layout).
// ---------------------------------------------------------------------------
__global__ __launch_bounds__(512, 2) void k_gemm(
    const u16* __restrict__ aprep, const u16* __restrict__ xbf,
    const float* __restrict__ partial, const float* __restrict__ bias,
    float* __restrict__ out) {
  extern __shared__ char smem[];
  float* fcl = (float*)(smem + 98304);       // 256 floats
  const int bid = blockIdx.x;
  const int dp = bid & 7;                    // d-pair -> XCD
  const int d = ((bid >> 3) & 1) ? (15 - dp) : dp;
  const int bt = bid >> 4;                   // 0..15 batch tile
  const int b0 = bt * 256;
  const int fr0 = d * 256;
  const int t = threadIdx.x;
  const int wave = t >> 6, lane = t & 63;
  const int lhi = lane >> 4, llo = lane & 15;
  const int wm = wave >> 2, wn = wave & 3;   // batch half / feature quarter
  const int kmask = ((llo >> 1) & 7) << 4;

  f32x4 acc[8][4] = {};

  // staging: op 0/1 = A(x) chunk j, op 2/3 = B(W) chunk j-2
  auto stage1 = [&](int slot, int kt, int op) {
    int j = op & 1;
    int c = j * 512 + t;                 // physical 16B chunk (0..1023)
    int cl = c ^ ((c >> 3) & 7);         // logical chunk (involution)
    int r = cl >> 2, kc = cl & 3;
    unsigned lbase = (unsigned)(slot * 32768 + (op >= 2 ? 16384 : 0) +
                                (j * 512 + wave * 64) * 16);
    const u16* g;
    if (op < 2) {
      int fbase = (kt < 8) ? (d * 256 + kt * 32)
                           : ((15 - d) * 256 + (kt - 8) * 32);
      g = xbf + (size_t)(b0 + r) * NF + fbase + kc * 8;
    } else {
      g = aprep + (size_t)(fr0 + r) * KTOT + kt * 32 + kc * 8;
    }
    __builtin_amdgcn_global_load_lds(
        (const __attribute__((address_space(1))) unsigned int*)g,
        (__attribute__((address_space(3))) unsigned int*)(smem + lbase),
        16, 0, 0);
  };
  auto stageK = [&](int slot, int kt) {
    #pragma unroll
    for (int op = 0; op < 4; ++op) stage1(slot, kt, op);
  };

  // fc for this block's 256 batches (overlaps staging latency)
  if (t < 256) {
    float fs = 0.f;
    #pragma unroll
    for (int i = 0; i < 32; ++i) fs += partial[i * BSN + b0 + t];
    fcl[t] = rsqrtf(fs * (1.0f / 4096.0f) + 1e-6f);
  }
  stageK(0, 0);
  stageK(1, 1);
  asm volatile("s_waitcnt vmcnt(4)\n\ts_barrier" ::: "memory");

  for (int kt = 0; kt < 16; ++kt) {
    const int slot = kt % 3;
    const char* sA = (const char*)smem + slot * 32768;
    const char* sB = sA + 16384;
    const int st_slot = (kt + 2) % 3;
    const bool do_st = kt < 14;
    bf16x8 af[4], bf0[2], bf1[2];

    // ---- phase 0: af(batch half 0) + bf0 ; stage A j=0
    #pragma unroll
    for (int i = 0; i < 4; ++i) {
      int row = wm * 128 + i * 16 + llo;
      af[i] = *reinterpret_cast<const bf16x8*>(sA + ((row * 64 + lhi * 16) ^ kmask));
    }
    #pragma unroll
    for (int j = 0; j < 2; ++j) {
      int row = wn * 64 + j * 16 + llo;
      bf0[j] = *reinterpret_cast<const bf16x8*>(sB + ((row * 64 + lhi * 16) ^ kmask));
    }
    if (do_st) stage1(st_slot, kt + 2, 0);
    __builtin_amdgcn_s_setprio(1);
    #pragma unroll
    for (int i = 0; i < 4; ++i)
      #pragma unroll
      for (int j = 0; j < 2; ++j)
        acc[i][j] = __builtin_amdgcn_mfma_f32_16x16x32_bf16(af[i], bf0[j], acc[i][j], 0, 0, 0);
    __builtin_amdgcn_s_setprio(0);

    // ---- phase 1: bf1 ; stage A j=1
    #pragma unroll
    for (int j = 0; j < 2; ++j) {
      int row = wn * 64 + 32 + j * 16 + llo;
      bf1[j] = *reinterpret_cast<const bf16x8*>(sB + ((row * 64 + lhi * 16) ^ kmask));
    }
    if (do_st) stage1(st_slot, kt + 2, 1);
    __builtin_amdgcn_s_setprio(1);
    #pragma unroll
    for (int i = 0; i < 4; ++i)
      #pragma unroll
      for (int j = 0; j < 2; ++j)
        acc[i][2 + j] = __builtin_amdgcn_mfma_f32_16x16x32_bf16(af[i], bf1[j], acc[i][2 + j], 0, 0, 0);
    __builtin_amdgcn_s_setprio(0);

    // ---- phase 2: af(batch half 1) ; stage B j=0
    #pragma unroll
    for (int i = 0; i < 4; ++i) {
      int row = wm * 128 + 64 + i * 16 + llo;
      af[i] = *reinterpret_cast<const bf16x8*>(sA + ((row * 64 + lhi * 16) ^ kmask));
    }
    if (do_st) stage1(st_slot, kt + 2, 2);
    __builtin_amdgcn_s_setprio(1);
    #pragma unroll
    for (int i = 0; i < 4; ++i)
      #pragma unroll
      for (int j = 0; j < 2; ++j)
        acc[4 + i][j] = __builtin_amdgcn_mfma_f32_16x16x32_bf16(af[i], bf0[j], acc[4 + i][j], 0, 0, 0);
    __builtin_amdgcn_s_setprio(0);

    // ---- phase 3: (no ds_read) ; stage B j=1 ; boundary wait
    if (do_st) stage1(st_slot, kt + 2, 3);
    __builtin_amdgcn_s_setprio(1);
    #pragma unroll
    for (int i = 0; i < 4; ++i)
      #pragma unroll
      for (int j = 0; j < 2; ++j)
        acc[4 + i][2 + j] = __builtin_amdgcn_mfma_f32_16x16x32_bf16(af[i], bf1[j], acc[4 + i][2 + j], 0, 0, 0);
    __builtin_amdgcn_s_setprio(0);
    if (kt < 14) {
      asm volatile("s_waitcnt vmcnt(4)\n\ts_barrier" ::: "memory");
    } else if (kt == 14) {
      asm volatile("s_waitcnt vmcnt(0)\n\ts_barrier" ::: "memory");
    }
  }

  // ---- epilogue: y[f][b] = relu(fc[b]*acc + bias[f]), float4 over batch
  #pragma unroll
  for (int m = 0; m < 8; ++m) {
    int lb = wm * 128 + m * 16 + lhi * 4;
    float4 fq = *reinterpret_cast<const float4*>(&fcl[lb]);
    #pragma unroll
    for (int n = 0; n < 4; ++n) {
      int fo = fr0 + wn * 64 + n * 16 + llo;
      float bv = bias[fo];
      float4 v;
      v.x = fmaxf(acc[m][n][0] * fq.x + bv, 0.f);
      v.y = fmaxf(acc[m][n][1] * fq.y + bv, 0.f);
      v.z = fmaxf(acc[m][n][2] * fq.z + bv, 0.f);
      v.w = fmaxf(acc[m][n][3] * fq.w + bv, 0.f);
      *reinterpret_cast<float4*>(out + (size_t)fo * BSN + b0 + lb) = v;
    }
  }
}

extern "C" void kernel_launch(void* const* d_in, const int* in_sizes, int n_in,
                              void* d_out, int out_size, void* d_ws, size_t ws_size,
                              hipStream_t stream) {
  (void)in_sizes; (void)n_in; (void)out_size; (void)ws_size;
  const float* x    = (const float*)d_in[0];
  const float* rms  = (const float*)d_in[1];
  const float* wu   = (const float*)d_in[2];
  const float* wl   = (const float*)d_in[3];
  const float* bias = (const float*)d_in[4];
  float* out = (float*)d_out;

  char* ws = (char*)d_ws;
  u16* xbf      = (u16*)ws;                      // 32 MiB  (x^T bf16)
  u16* aprep    = (u16*)(ws + 33554432);         // 4 MiB   (folded weights)
  float* partial = (float*)(ws + 37748736);      // 512 KiB (sumsq partials)

  k_pre<<<2048, 256, 0, stream>>>(x, wu, wl, rms, aprep, xbf, partial);
  k_gemm<<<256, 512, 99328, stream>>>(aprep, xbf, partial, bias, out);
}